// Round 11
// baseline (380.369 us; speedup 1.0000x reference)
//
#include <hip/hip_runtime.h>

#define Bb 8
#define Tt 512
#define Ff 256
#define Cc 16
#define TF (Tt*Ff)
#define TROW 528
#define FROW 272
#define CELL 64
#define PROW 80                                    // staged cells per window row
#define PROWB (PROW*CELL)                          // 5120 B
#define BUFBYTES ((size_t)Bb*TROW*FROW*CELL)       // 73,531,392

typedef __attribute__((ext_vector_type(8))) short short8;
typedef __attribute__((ext_vector_type(4))) float f32x4;

typedef const __attribute__((address_space(1))) void* gas1_t;
typedef __attribute__((address_space(3))) void* las3_t;
#define GLOAD_LDS(g, l) __builtin_amdgcn_global_load_lds((gas1_t)(const void*)(g), (las3_t)(void*)(l), 16, 0, 0)

// s_waitcnt immediates (gfx9 encoding: vmcnt[3:0]|[15:14], expcnt[6:4], lgkmcnt[11:8])
#define WAIT_VM0  0x0F70
#define WAIT_VM32 0x8F70
#define WAIT_VM48 0xCF70
#define WAIT_LGKM0 0xC07F

__device__ __forceinline__ float fexp2(float x) { return __builtin_amdgcn_exp2f(x); }

__device__ __forceinline__ float fast_sigmoid(float x) {
    return __builtin_amdgcn_rcpf(1.0f + fexp2(-1.4426950408889634f * x));
}
__device__ __forceinline__ float fast_tanh(float x) {
    return 1.0f - 2.0f * __builtin_amdgcn_rcpf(fexp2(2.8853900817779268f * x) + 1.0f);
}

__device__ __forceinline__ unsigned short bf16_rne(float x) {
    unsigned u = __float_as_uint(x);
    u += 0x7fffu + ((u >> 16) & 1u);
    return (unsigned short)(u >> 16);
}
__device__ __forceinline__ float bf16_to_f(unsigned short h) {
    return __uint_as_float(((unsigned)h) << 16);
}
__device__ __forceinline__ f32x4 mfma_bf16(short8 a, short8 b, f32x4 c) {
    return __builtin_amdgcn_mfma_f32_16x16x32_bf16(a, b, c, 0, 0, 0);
}

// paired helpers
__device__ __forceinline__ float2 f2fma(float2 a, float s, float2 c) {
    return make_float2(fmaf(a.x, s, c.x), fmaf(a.y, s, c.y));
}
__device__ __forceinline__ float2 sig2(float2 u) {
    float e0 = fexp2(-u.x), e1 = fexp2(-u.y);
    return make_float2(__builtin_amdgcn_rcpf(1.f + e0), __builtin_amdgcn_rcpf(1.f + e1));
}
__device__ __forceinline__ float2 tanh2(float2 u) {
    float e0 = fexp2(u.x + u.x), e1 = fexp2(u.y + u.y);
    return make_float2(1.f - 2.f * __builtin_amdgcn_rcpf(e0 + 1.f),
                       1.f - 2.f * __builtin_amdgcn_rcpf(e1 + 1.f));
}

// ---------- merged setup: blocks 0-2 = BN-fold+split weights for convs 2-4;
// blocks 3..786 = zero halo pads; blocks 787.. = gate1 conv (disjoint cells) ----
__global__ __launch_bounds__(256)
void setup_all(const float* __restrict__ x1, const float* __restrict__ w1, const float* __restrict__ b1,
               const float* __restrict__ gm1, const float* __restrict__ bt1,
               const float* __restrict__ mn1, const float* __restrict__ vr1,
               const float* __restrict__ w2, const float* __restrict__ b2, const float* __restrict__ gm2,
               const float* __restrict__ bt2, const float* __restrict__ mn2, const float* __restrict__ vr2,
               const float* __restrict__ w3, const float* __restrict__ b3, const float* __restrict__ gm3,
               const float* __restrict__ bt3, const float* __restrict__ mn3, const float* __restrict__ vr3,
               const float* __restrict__ w4, const float* __restrict__ b4, const float* __restrict__ gm4,
               const float* __restrict__ bt4, const float* __restrict__ mn4, const float* __restrict__ vr4,
               char* __restrict__ bufA, char* __restrict__ bufB,
               char* __restrict__ wpreAll, float* __restrict__ bpreAll)
{
    const int blk = blockIdx.x;
    const int tid = threadIdx.x;
    if (blk < 3) {
        const float *w, *bias, *gamma, *beta, *mean, *var;
        if (blk == 0)      { w = w2; bias = b2; gamma = gm2; beta = bt2; mean = mn2; var = vr2; }
        else if (blk == 1) { w = w3; bias = b3; gamma = gm3; beta = bt3; mean = mn3; var = vr3; }
        else               { w = w4; bias = b4; gamma = gm4; beta = bt4; mean = mn4; var = vr4; }
        char* wpre = wpreAll + blk * 20480;
        float* bpre = bpreAll + blk * 32;
        if (tid < 32) {
            float s = gamma[tid] * rsqrtf(var[tid] + 1e-5f);
            bpre[tid] = (bias[tid] - mean[tid]) * s + beta[tid];
        }
        for (int i = tid; i < 4608; i += 256) {
            int co = i / 144, r = i - co * 144;
            int ci = r / 9, tap = r - ci * 9;
            float s = gamma[co] * rsqrtf(var[co] + 1e-5f);
            float wv = w[(co * 16 + ci) * 9 + tap] * s;
            unsigned short hi = bf16_rne(wv);
            unsigned short lo = bf16_rne(wv - bf16_to_f(hi));
            int ks = tap >> 1, tp = tap & 1;
            int kl = tp * 16 + ci;
            int qq = kl >> 3, jj = kl & 7;
            int sub = qq ^ (co & 3);
            *(unsigned short*)(wpre + ((0 * 5 + ks) * 32 + co) * 64 + sub * 16 + jj * 2) = hi;
            *(unsigned short*)(wpre + ((1 * 5 + ks) * 32 + co) * 64 + sub * 16 + jj * 2) = lo;
        }
        for (int i = tid; i < 1024; i += 256) {
            int p = i >> 9, rem = i & 511;
            int co = rem >> 4, kl = 16 + (rem & 15);
            int qq = kl >> 3, jj = kl & 7;
            int sub = qq ^ (co & 3);
            *(unsigned short*)(wpre + ((p * 5 + 4) * 32 + co) * 64 + sub * 16 + jj * 2) = 0;
        }
    } else if (blk < 787) {
        int idx = (blk - 3) * 256 + tid;      // 200704 cells total
        int which = idx >= 100352;
        int r0 = which ? idx - 100352 : idx;
        int b = r0 / 12544, c = r0 - b * 12544;
        int tp, fp;
        if (c < 4352) { int row = c / 272; fp = c - row * 272; tp = row < 8 ? row : 512 + row; }
        else { int c2 = c - 4352; tp = 8 + (c2 >> 4); int fi = c2 & 15; fp = fi < 8 ? fi : 256 + fi; }
        char* base = (which ? bufB : bufA) + ((size_t)(b * TROW + tp) * FROW + fp) * CELL;
        float4 z = make_float4(0.f, 0.f, 0.f, 0.f);
        float4* p = (float4*)base;
        p[0] = z; p[1] = z; p[2] = z; p[3] = z;
    } else {
        // ---- gate1 conv (CIN=2, dil=1), tiled, whole-chunk stores ----
        __shared__ float xs[2][6][66];
        __shared__ float wl[18 * 32];
        __shared__ float bnsL[32], bnoL[32];
        int bb = blk - 787;                   // 4096 blocks: [b(8)][ty(128)][fx(4)]
        int fx = bb & 3;
        int ty = (bb >> 2) & 127;
        int b  = bb >> 9;
        const int f0 = fx * 64;
        const int t0 = ty * 4;
        const int fl = tid & 63;
        const int tr = (tid >> 6) & 1;
        const int h  = tid >> 7;

        if (tid < 32) {
            float s = gm1[tid] * rsqrtf(vr1[tid] + 1e-5f);
            bnsL[tid] = s;
            bnoL[tid] = (b1[tid] - mn1[tid]) * s + bt1[tid];
        }
        for (int i = tid; i < 576; i += 256) {
            int co = i & 31, rest = i >> 5;
            int ci = rest / 9, tap = rest - ci * 9;
            wl[rest * 32 + co] = w1[(co * 2 + ci) * 9 + tap];
        }
        for (int i = tid; i < 792; i += 256) {
            int ci = i / 396, r = i - ci * 396;
            int row = r / 66, col = r - row * 66;
            int t_in = t0 + row - 1, f_in = f0 + col - 1;
            float v = 0.f;
            if (t_in >= 0 && t_in < Tt && f_in >= 0 && f_in < Ff)
                v = x1[((size_t)(b * 2 + ci) * Tt + t_in) * Ff + f_in];
            xs[ci][row][col] = v;
        }
        __syncthreads();

        float acc[2][16];
        #pragma unroll
        for (int q = 0; q < 2; q++)
            #pragma unroll
            for (int j = 0; j < 16; j++) acc[q][j] = 0.f;

        #pragma unroll
        for (int ci = 0; ci < 2; ci++) {
            float win[4][3];
            #pragma unroll
            for (int r = 0; r < 4; r++)
                #pragma unroll
                for (int c = 0; c < 3; c++)
                    win[r][c] = xs[ci][2 * tr + r][fl + c];
            #pragma unroll
            for (int dt = 0; dt < 3; dt++)
                #pragma unroll
                for (int kf = 0; kf < 3; kf++) {
                    float xv0 = win[dt][kf];
                    float xv1 = win[dt + 1][kf];
                    const float* wrow = wl + (ci * 9 + dt * 3 + kf) * 32 + h * 8;
                    float wv[16];
                    *(float4*)(wv)      = *(const float4*)(wrow);
                    *(float4*)(wv + 4)  = *(const float4*)(wrow + 4);
                    *(float4*)(wv + 8)  = *(const float4*)(wrow + 16);
                    *(float4*)(wv + 12) = *(const float4*)(wrow + 20);
                    #pragma unroll
                    for (int j = 0; j < 16; j++) {
                        acc[0][j] = fmaf(xv0, wv[j], acc[0][j]);
                        acc[1][j] = fmaf(xv1, wv[j], acc[1][j]);
                    }
                }
        }

        #pragma unroll
        for (int q = 0; q < 2; q++) {
            int t = t0 + 2 * tr + q;
            int fp = f0 + fl + 8;
            int sw = fp & 3;
            char* cell = bufA + ((size_t)(b * TROW + t + 8) * FROW + fp) * CELL;
            unsigned short hi[8], lo[8];
            #pragma unroll
            for (int j = 0; j < 8; j++) {
                int ca = h * 8 + j, cg = 16 + h * 8 + j;
                float av = acc[q][j]     * bnsL[ca] + bnoL[ca];
                float gv = acc[q][8 + j] * bnsL[cg] + bnoL[cg];
                float r = fast_tanh(av) * fast_sigmoid(gv);
                hi[j] = bf16_rne(r);
                lo[j] = bf16_rne(r - bf16_to_f(hi[j]));
            }
            uint4 H, L;
            H.x = (unsigned)hi[0] | ((unsigned)hi[1] << 16);
            H.y = (unsigned)hi[2] | ((unsigned)hi[3] << 16);
            H.z = (unsigned)hi[4] | ((unsigned)hi[5] << 16);
            H.w = (unsigned)hi[6] | ((unsigned)hi[7] << 16);
            L.x = (unsigned)lo[0] | ((unsigned)lo[1] << 16);
            L.y = (unsigned)lo[2] | ((unsigned)lo[3] << 16);
            L.z = (unsigned)lo[4] | ((unsigned)lo[5] << 16);
            L.w = (unsigned)lo[6] | ((unsigned)lo[7] << 16);
            *(uint4*)(cell + ((h)     ^ sw) * 16) = H;
            *(uint4*)(cell + ((2 + h) ^ sw) * 16) = L;
        }
    }
}

// ---------- convs 2-4: barrier-free wave-private MFMA implicit GEMM ----------
// Each wave: 2 outputs {t0, t0+d} x 64 f. Stages its OWN 4 rows x 80 cells
// (20 KB) via global_load_lds, waits vmcnt(0) (wave-local, no __syncthreads),
// computes 480 wave-MFMAs, epilogue transpose through its own LDS region.
template<int DIL, int WRITE_F32>
__global__ __launch_bounds__(128, 2)
void gate_mfma(const char* __restrict__ actIn, const char* __restrict__ wpre,
               const float* __restrict__ bpre, char* __restrict__ outBuf)
{
    __shared__ char L[2][4 * PROWB];   // 2 x 20480 B, wave-private halves
    const int tg = blockIdx.x, b = blockIdx.z;
    const int tid = threadIdx.x;
    const int wv = tid >> 6, lane = tid & 63;
    const int n = lane & 15, q = lane >> 4;
    constexpr int GPC2 = 256 / DIL;         // 2-output groups per residue class
    const int rcl = tg / GPC2, m = tg - rcl * GPC2;
    const int t0 = rcl + 2 * m * DIL;
    const int fs = blockIdx.y * 2 + wv;     // f-strip 0..3
    const int F0 = fs * 64;                 // window start (padded coords)
    char* Lw = L[wv];

    // A-fragments (weights) from global (L2-hot), registers
    short8 aH[5][2], aL[5][2];
    #pragma unroll
    for (int ks = 0; ks < 5; ks++)
        #pragma unroll
        for (int ct = 0; ct < 2; ct++) {
            int co = ct * 16 + n;
            int sub = q ^ (co & 3);
            aH[ks][ct] = *(const short8*)(wpre + (size_t)((0 * 5 + ks) * 32 + co) * 64 + sub * 16);
            aL[ks][ct] = *(const short8*)(wpre + (size_t)((5 + ks) * 32 + co) * 64 + sub * 16);
        }

    // stage 4 rows (t0-d .. t0+2d) x 80 cells, wave-private
    #pragma unroll
    for (int r = 0; r < 4; r++) {
        int tp = t0 + 8 + (r - 1) * DIL;
        const char* src = actIn + ((size_t)(b * TROW + tp) * FROW + F0) * CELL + lane * 16;
        char* dst = Lw + r * PROWB;
        #pragma unroll
        for (int s = 0; s < 5; s++)
            GLOAD_LDS(src + s * 1024, dst + s * 1024);
    }
    __builtin_amdgcn_sched_barrier(0);
    __builtin_amdgcn_s_waitcnt(WAIT_VM0);
    __builtin_amdgcn_sched_barrier(0);

    f32x4 acc[2][4][2] = {};   // [jj][nt][ct]

    #pragma unroll
    for (int ks = 0; ks < 5; ks++) {
        const int tapA = 2 * ks;
        const int tapB = (2 * ks + 1 > 8) ? 8 : 2 * ks + 1;
        const int rowA = tapA / 3, dfA = (tapA % 3 - 1) * DIL;
        const int rowB = tapB / 3, dfB = (tapB % 3 - 1) * DIL;
        int tapSel = q >> 1;
        int rowt = tapSel ? rowB : rowA;       // t-tap 0..2
        int df  = tapSel ? dfB : dfA;
        int cih = q & 1;
        #pragma unroll
        for (int jj = 0; jj < 2; jj++) {
            const char* rbase = Lw + (jj + rowt) * PROWB;
            #pragma unroll
            for (int nt = 0; nt < 4; nt++) {
                int fp = 8 + nt * 16 + n + df;       // window-local, parity == global
                const char* cell = rbase + fp * CELL;
                short8 bH = *(const short8*)(cell + ((cih) ^ (fp & 3)) * 16);
                short8 bL = *(const short8*)(cell + ((2 + cih) ^ (fp & 3)) * 16);
                #pragma unroll
                for (int ct = 0; ct < 2; ct++) {
                    acc[jj][nt][ct] = mfma_bf16(aH[ks][ct], bH, acc[jj][nt][ct]);
                    acc[jj][nt][ct] = mfma_bf16(aL[ks][ct], bH, acc[jj][nt][ct]);
                    acc[jj][nt][ct] = mfma_bf16(aH[ks][ct], bL, acc[jj][nt][ct]);
                }
            }
        }
    }

    // epilogue: GLU -> wave-private LDS transpose -> contiguous chunk stores
    float4 bA = *(const float4*)(bpre + q * 4);
    float4 bG = *(const float4*)(bpre + 16 + q * 4);

    if (WRITE_F32) {
        float* Ef = (float*)Lw;              // [jj(2)][c(16)][fl(64)]
        #pragma unroll
        for (int jj = 0; jj < 2; jj++)
            #pragma unroll
            for (int nt = 0; nt < 4; nt++) {
                float r[4];
                r[0] = fast_tanh(acc[jj][nt][0].x + bA.x) * fast_sigmoid(acc[jj][nt][1].x + bG.x);
                r[1] = fast_tanh(acc[jj][nt][0].y + bA.y) * fast_sigmoid(acc[jj][nt][1].y + bG.y);
                r[2] = fast_tanh(acc[jj][nt][0].z + bA.z) * fast_sigmoid(acc[jj][nt][1].z + bG.z);
                r[3] = fast_tanh(acc[jj][nt][0].w + bA.w) * fast_sigmoid(acc[jj][nt][1].w + bG.w);
                int fl = nt * 16 + n;
                #pragma unroll
                for (int j = 0; j < 4; j++)
                    Ef[(jj * 16 + q * 4 + j) * 64 + fl] = r[j];
            }
        __builtin_amdgcn_sched_barrier(0);
        __builtin_amdgcn_s_waitcnt(WAIT_LGKM0);
        __builtin_amdgcn_sched_barrier(0);
        float* gp = (float*)outBuf;
        int c = lane >> 2, p = lane & 3;
        #pragma unroll
        for (int jj = 0; jj < 2; jj++) {
            int tt = t0 + jj * DIL;
            float* dst = gp + (size_t)(b * 16 + c) * TF + tt * Ff + F0 + p * 16;
            const float* srcE = Ef + (jj * 16 + c) * 64 + p * 16;
            #pragma unroll
            for (int k = 0; k < 4; k++)
                *(float4*)(dst + k * 4) = *(const float4*)(srcE + k * 4);
        }
    } else {
        char* Eo = Lw;                        // [jj(2)][fl(64)][64B]
        #pragma unroll
        for (int jj = 0; jj < 2; jj++)
            #pragma unroll
            for (int nt = 0; nt < 4; nt++) {
                float r[4];
                r[0] = fast_tanh(acc[jj][nt][0].x + bA.x) * fast_sigmoid(acc[jj][nt][1].x + bG.x);
                r[1] = fast_tanh(acc[jj][nt][0].y + bA.y) * fast_sigmoid(acc[jj][nt][1].y + bG.y);
                r[2] = fast_tanh(acc[jj][nt][0].z + bA.z) * fast_sigmoid(acc[jj][nt][1].z + bG.z);
                r[3] = fast_tanh(acc[jj][nt][0].w + bA.w) * fast_sigmoid(acc[jj][nt][1].w + bG.w);
                int fl = nt * 16 + n;
                int sw = (F0 + 8 + fl) & 3;
                unsigned short h[4], l[4];
                #pragma unroll
                for (int j = 0; j < 4; j++) {
                    h[j] = bf16_rne(r[j]);
                    l[j] = bf16_rne(r[j] - bf16_to_f(h[j]));
                }
                uint2 hw, lw;
                hw.x = (unsigned)h[0] | ((unsigned)h[1] << 16);
                hw.y = (unsigned)h[2] | ((unsigned)h[3] << 16);
                lw.x = (unsigned)l[0] | ((unsigned)l[1] << 16);
                lw.y = (unsigned)l[2] | ((unsigned)l[3] << 16);
                int inner = (q & 1) * 8;
                char* base = Eo + (jj * 64 + fl) * 64;
                *(uint2*)(base + (((q >> 1) ^ sw) * 16) + inner) = hw;
                *(uint2*)(base + (((2 + (q >> 1)) ^ sw) * 16) + inner) = lw;
            }
        __builtin_amdgcn_sched_barrier(0);
        __builtin_amdgcn_s_waitcnt(WAIT_LGKM0);
        __builtin_amdgcn_sched_barrier(0);
        #pragma unroll
        for (int jj = 0; jj < 2; jj++) {
            int tt = t0 + jj * DIL;
            char* dstRow = outBuf + ((size_t)(b * TROW + tt + 8) * FROW + F0 + 8) * CELL + lane * 64;
            const char* srcL = Eo + jj * 4096 + lane * 64;
            #pragma unroll
            for (int k = 0; k < 4; k++)
                *(uint4*)(dstRow + k * 16) = *(const uint4*)(srcL + k * 16);
        }
    }
}

// ---------- grouped GRU (H=2) + fused out_w partial dot ----------
// 3-buffer LDS-DMA pipeline, staged 2 chunks ahead; exact vmcnt accounting
// (vmcnt(48) steady state). part: [b][g][fsl(4)][tpair(256)][lane(64)][2]
__global__ __launch_bounds__(64)
void gru_kernel(const float* __restrict__ xin, const float* __restrict__ wih,
                const float* __restrict__ whh, const float* __restrict__ bih,
                const float* __restrict__ bhh, const float* __restrict__ out_w,
                float* __restrict__ part)
{
    __shared__ float ldsF[3 * 4096];   // 3 x 16 KB rotation
    const int lane = threadIdx.x;
    const int fsl = blockIdx.x & 3;
    const int g = (blockIdx.x >> 2) & 7;
    const int b = blockIdx.x >> 5;

    const float L2E = 1.4426950408889634f;
    float2 WiX[3], WiY[3], WhX[3], WhY[3], Bi[3], Bh[3];
    #pragma unroll
    for (int p = 0; p < 3; p++) {
        WiX[p] = make_float2(wih[g * 12 + (2 * p) * 2 + 0] * L2E, wih[g * 12 + (2 * p + 1) * 2 + 0] * L2E);
        WiY[p] = make_float2(wih[g * 12 + (2 * p) * 2 + 1] * L2E, wih[g * 12 + (2 * p + 1) * 2 + 1] * L2E);
        WhX[p] = make_float2(whh[g * 12 + (2 * p) * 2 + 0] * L2E, whh[g * 12 + (2 * p + 1) * 2 + 0] * L2E);
        WhY[p] = make_float2(whh[g * 12 + (2 * p) * 2 + 1] * L2E, whh[g * 12 + (2 * p + 1) * 2 + 1] * L2E);
        Bi[p] = make_float2(bih[g * 6 + 2 * p] * L2E, bih[g * 6 + 2 * p + 1] * L2E);
        Bh[p] = make_float2(bhh[g * 6 + 2 * p] * L2E, bhh[g * 6 + 2 * p + 1] * L2E);
    }
    const float ow0 = out_w[2 * g], ow1 = out_w[2 * g + 1];

    const int sub = lane & 15, cch = (lane >> 4) & 1, tpr = lane >> 5;
    const float* gsrc = xin + ((size_t)(b * Cc + 2 * g + cch) * Tt + tpr) * Ff + fsl * 64 + sub * 4;

    float* poBase = part + ((size_t)((b * 8 + g) * 4 + fsl)) * 32768;

    #define STAGE(bsel, chunk)                                                \
    {                                                                         \
        char* ldst = (char*)(ldsF + (bsel) * 4096);                           \
        const float* gs = gsrc + (size_t)(chunk) * 32 * Ff;                   \
        _Pragma("unroll")                                                     \
        for (int j = 0; j < 16; j++)                                          \
            GLOAD_LDS(gs + 2 * j * Ff, ldst + j * 1024);                      \
    }

    float2 hP = make_float2(0.f, 0.f);
    STAGE(0, 0); STAGE(1, 1); STAGE(2, 2);

    for (int k = 0; k < 16; k++) {
        if (k) {
            int cs = k + 2; if (cs >= 16) cs -= 16;
            int bs = k + 2; bs -= (bs / 3) * 3;      // (k+2)%3
            STAGE(bs, cs);
            __builtin_amdgcn_sched_barrier(0);
            __builtin_amdgcn_s_waitcnt(WAIT_VM48);
            __builtin_amdgcn_sched_barrier(0);
        } else {
            __builtin_amdgcn_sched_barrier(0);
            __builtin_amdgcn_s_waitcnt(WAIT_VM32);
            __builtin_amdgcn_sched_barrier(0);
        }
        int bc = k - (k / 3) * 3;                    // k%3
        const float* cbase = ldsF + bc * 4096;
        float2 outR[16];
        #pragma unroll
        for (int tt = 0; tt < 32; tt++) {
            const float* cell = cbase + (tt >> 1) * 256 + (tt & 1) * 128;
            float x0 = cell[lane];
            float x1 = cell[64 + lane];
            float2 giR = f2fma(WiY[0], x1, f2fma(WiX[0], x0, Bi[0]));
            float2 giZ = f2fma(WiY[1], x1, f2fma(WiX[1], x0, Bi[1]));
            float2 giN = f2fma(WiY[2], x1, f2fma(WiX[2], x0, Bi[2]));
            float2 ghR = f2fma(WhY[0], hP.y, f2fma(WhX[0], hP.x, Bh[0]));
            float2 ghZ = f2fma(WhY[1], hP.y, f2fma(WhX[1], hP.x, Bh[1]));
            float2 ghN = f2fma(WhY[2], hP.y, f2fma(WhX[2], hP.x, Bh[2]));
            float2 rP = sig2(make_float2(giR.x + ghR.x, giR.y + ghR.y));
            float2 zP = sig2(make_float2(giZ.x + ghZ.x, giZ.y + ghZ.y));
            float2 nP = tanh2(make_float2(fmaf(rP.x, ghN.x, giN.x), fmaf(rP.y, ghN.y, giN.y)));
            hP = make_float2(fmaf(zP.x, hP.x - nP.x, nP.x), fmaf(zP.y, hP.y - nP.y, nP.y));
            float o = fmaf(hP.x, ow0, hP.y * ow1);
            if (tt & 1) outR[tt >> 1].y = o; else outR[tt >> 1].x = o;
        }
        #pragma unroll
        for (int j = 0; j < 16; j++)
            *(float2*)(poBase + (k * 16 + j) * 128 + lane * 2) = outR[j];
    }
    #undef STAGE
}

// sum 8 group partials (part layout) + out_b -> (B,1,T,F)
__global__ __launch_bounds__(256)
void out_kernel(const float* __restrict__ part, const float* __restrict__ out_b,
                float* __restrict__ out)
{
    int idx = blockIdx.x * 256 + threadIdx.x;    // 524288 total: [b][tpair][f]
    int f = idx & 255;
    int tp = (idx >> 8) & 255;
    int b = idx >> 16;
    int fsl = f >> 6, ln = f & 63;
    const float* base = part + ((size_t)(b * 8) * 4 + fsl) * 32768 + tp * 128 + ln * 2;
    float ob = out_b[0];
    float s0 = ob, s1 = ob;
    #pragma unroll
    for (int g = 0; g < 8; g++) {
        float2 v = *(const float2*)(base + (size_t)g * 131072);
        s0 += v.x; s1 += v.y;
    }
    float* op = out + ((size_t)b * Tt + 2 * tp) * Ff + f;
    op[0] = s0;
    op[Ff] = s1;
}

extern "C" void kernel_launch(void* const* d_in, const int* in_sizes, int n_in,
                              void* d_out, int out_size, void* d_ws, size_t ws_size,
                              hipStream_t stream) {
    char* bufA = (char*)d_ws;
    char* bufB = bufA + BUFBYTES;
    char* wpre = bufB + BUFBYTES;
    float* bpre = (float*)(wpre + 3 * 20480);

    setup_all<<<787 + 4096, 256, 0, stream>>>(
        (const float*)d_in[0],
        (const float*)d_in[1],  (const float*)d_in[2],  (const float*)d_in[3],
        (const float*)d_in[4],  (const float*)d_in[5],  (const float*)d_in[6],
        (const float*)d_in[7],  (const float*)d_in[8],  (const float*)d_in[9],
        (const float*)d_in[10], (const float*)d_in[11], (const float*)d_in[12],
        (const float*)d_in[13], (const float*)d_in[14], (const float*)d_in[15],
        (const float*)d_in[16], (const float*)d_in[17], (const float*)d_in[18],
        (const float*)d_in[19], (const float*)d_in[20], (const float*)d_in[21],
        (const float*)d_in[22], (const float*)d_in[23], (const float*)d_in[24],
        bufA, bufB, wpre, bpre);

    dim3 grid(256, 2, Bb), blk(128);
    gate_mfma<2, 0><<<grid, blk, 0, stream>>>(bufA, wpre,         bpre,      bufB);
    gate_mfma<4, 0><<<grid, blk, 0, stream>>>(bufB, wpre + 20480, bpre + 32, bufA);
    gate_mfma<8, 1><<<grid, blk, 0, stream>>>(bufA, wpre + 40960, bpre + 64, bufB);

    // GRU reads fp32 gruIn (bufB), writes partials into bufA
    gru_kernel<<<Bb * 8 * 4, 64, 0, stream>>>(
        (const float*)bufB, (const float*)d_in[25], (const float*)d_in[26], (const float*)d_in[27],
        (const float*)d_in[28], (const float*)d_in[29], (float*)bufA);

    out_kernel<<<2048, 256, 0, stream>>>(
        (const float*)bufA, (const float*)d_in[30], (float*)d_out);
}

// Round 12
// 302.948 us; speedup vs baseline: 1.2556x; 1.2556x over previous
//
#include <hip/hip_runtime.h>

#define Bb 8
#define Tt 512
#define Ff 256
#define Cc 16
#define TF (Tt*Ff)
#define TROW 528
#define FROW 272
#define CELL 32
#define WROWB (144*CELL)                           // 4608 B per staged window row
#define BUFBYTES ((size_t)Bb*TROW*FROW*CELL)       // 36,765,696

typedef _Float16 half8 __attribute__((ext_vector_type(8)));
typedef __attribute__((ext_vector_type(4))) float f32x4;

typedef const __attribute__((address_space(1))) void* gas1_t;
typedef __attribute__((address_space(3))) void* las3_t;
#define GLOAD_LDS(g, l) __builtin_amdgcn_global_load_lds((gas1_t)(const void*)(g), (las3_t)(void*)(l), 16, 0, 0)

#define WAIT_VM32 0x8F70
#define WAIT_VM48 0xCF70

__device__ __forceinline__ float fexp2(float x) { return __builtin_amdgcn_exp2f(x); }

__device__ __forceinline__ float fast_sigmoid(float x) {
    return __builtin_amdgcn_rcpf(1.0f + fexp2(-1.4426950408889634f * x));
}
__device__ __forceinline__ float fast_tanh(float x) {
    return 1.0f - 2.0f * __builtin_amdgcn_rcpf(fexp2(2.8853900817779268f * x) + 1.0f);
}

__device__ __forceinline__ unsigned short hbits(float x) {
    _Float16 h = (_Float16)x;
    return __builtin_bit_cast(unsigned short, h);
}
__device__ __forceinline__ float h2f(unsigned short u) {
    return (float)__builtin_bit_cast(_Float16, u);
}
__device__ __forceinline__ f32x4 mfma_f16(half8 a, half8 b, f32x4 c) {
    return __builtin_amdgcn_mfma_f32_16x16x32_f16(a, b, c, 0, 0, 0);
}

// paired helpers for gru
__device__ __forceinline__ float2 f2fma(float2 a, float s, float2 c) {
    return make_float2(fmaf(a.x, s, c.x), fmaf(a.y, s, c.y));
}
__device__ __forceinline__ float2 sig2(float2 u) {
    float e0 = fexp2(-u.x), e1 = fexp2(-u.y);
    return make_float2(__builtin_amdgcn_rcpf(1.f + e0), __builtin_amdgcn_rcpf(1.f + e1));
}
__device__ __forceinline__ float2 tanh2(float2 u) {
    float e0 = fexp2(u.x + u.x), e1 = fexp2(u.y + u.y);
    return make_float2(1.f - 2.f * __builtin_amdgcn_rcpf(e0 + 1.f),
                       1.f - 2.f * __builtin_amdgcn_rcpf(e1 + 1.f));
}

// ---------- merged setup: blocks 0-2 = BN-fold + fp16 hi/lo weight planes;
// blocks 3..786 = zero halo pads; blocks 787.. = gate1 conv ----------
__global__ __launch_bounds__(256)
void setup_all(const float* __restrict__ x1, const float* __restrict__ w1, const float* __restrict__ b1,
               const float* __restrict__ gm1, const float* __restrict__ bt1,
               const float* __restrict__ mn1, const float* __restrict__ vr1,
               const float* __restrict__ w2, const float* __restrict__ b2, const float* __restrict__ gm2,
               const float* __restrict__ bt2, const float* __restrict__ mn2, const float* __restrict__ vr2,
               const float* __restrict__ w3, const float* __restrict__ b3, const float* __restrict__ gm3,
               const float* __restrict__ bt3, const float* __restrict__ mn3, const float* __restrict__ vr3,
               const float* __restrict__ w4, const float* __restrict__ b4, const float* __restrict__ gm4,
               const float* __restrict__ bt4, const float* __restrict__ mn4, const float* __restrict__ vr4,
               char* __restrict__ bufA, char* __restrict__ bufB,
               char* __restrict__ wpreAll, float* __restrict__ bpreAll)
{
    const int blk = blockIdx.x;
    const int tid = threadIdx.x;
    if (blk < 3) {
        const float *w, *bias, *gamma, *beta, *mean, *var;
        if (blk == 0)      { w = w2; bias = b2; gamma = gm2; beta = bt2; mean = mn2; var = vr2; }
        else if (blk == 1) { w = w3; bias = b3; gamma = gm3; beta = bt3; mean = mn3; var = vr3; }
        else               { w = w4; bias = b4; gamma = gm4; beta = bt4; mean = mn4; var = vr4; }
        char* wpre = wpreAll + blk * 20480;
        float* bpre = bpreAll + blk * 32;
        if (tid < 32) {
            float s = gamma[tid] * rsqrtf(var[tid] + 1e-5f);
            bpre[tid] = (bias[tid] - mean[tid]) * s + beta[tid];
        }
        for (int i = tid; i < 4608; i += 256) {
            int co = i / 144, r = i - co * 144;
            int ci = r / 9, tap = r - ci * 9;
            float s = gamma[co] * rsqrtf(var[co] + 1e-5f);
            float wv = w[(co * 16 + ci) * 9 + tap] * s;
            unsigned short hi = hbits(wv);
            unsigned short lo = hbits((wv - h2f(hi)) * 2048.0f);
            int ks = tap >> 1, tp = tap & 1;
            int kl = tp * 16 + ci;
            int qq = kl >> 3, jj = kl & 7;
            int sub = qq ^ (co & 3);
            *(unsigned short*)(wpre + ((0 * 5 + ks) * 32 + co) * 64 + sub * 16 + jj * 2) = hi;
            *(unsigned short*)(wpre + ((1 * 5 + ks) * 32 + co) * 64 + sub * 16 + jj * 2) = lo;
        }
        // zero pad half of k-step 4 (tap 9), both planes
        for (int i = tid; i < 1024; i += 256) {
            int p = i >> 9, rem = i & 511;
            int co = rem >> 4, kl = 16 + (rem & 15);
            int qq = kl >> 3, jj = kl & 7;
            int sub = qq ^ (co & 3);
            *(unsigned short*)(wpre + ((p * 5 + 4) * 32 + co) * 64 + sub * 16 + jj * 2) = 0;
        }
    } else if (blk < 787) {
        int idx = (blk - 3) * 256 + tid;      // 200704 halo cells total
        int which = idx >= 100352;
        int r0 = which ? idx - 100352 : idx;
        int b = r0 / 12544, c = r0 - b * 12544;
        int tp, fp;
        if (c < 4352) { int row = c / 272; fp = c - row * 272; tp = row < 8 ? row : 512 + row; }
        else { int c2 = c - 4352; tp = 8 + (c2 >> 4); int fi = c2 & 15; fp = fi < 8 ? fi : 256 + fi; }
        char* base = (which ? bufB : bufA) + ((size_t)(b * TROW + tp) * FROW + fp) * CELL;
        float4 z = make_float4(0.f, 0.f, 0.f, 0.f);
        float4* p = (float4*)base;
        p[0] = z; p[1] = z;
    } else {
        // ---- gate1 conv (CIN=2, dil=1), tiled, fp16 cell output ----
        __shared__ float xs[2][6][66];
        __shared__ float wl[18 * 32];
        __shared__ float bnsL[32], bnoL[32];
        int bb = blk - 787;                   // 4096 blocks: [b(8)][ty(128)][fx(4)]
        int fx = bb & 3;
        int ty = (bb >> 2) & 127;
        int b  = bb >> 9;
        const int f0 = fx * 64;
        const int t0 = ty * 4;
        const int fl = tid & 63;
        const int tr = (tid >> 6) & 1;
        const int h  = tid >> 7;

        if (tid < 32) {
            float s = gm1[tid] * rsqrtf(vr1[tid] + 1e-5f);
            bnsL[tid] = s;
            bnoL[tid] = (b1[tid] - mn1[tid]) * s + bt1[tid];
        }
        for (int i = tid; i < 576; i += 256) {
            int co = i & 31, rest = i >> 5;
            int ci = rest / 9, tap = rest - ci * 9;
            wl[rest * 32 + co] = w1[(co * 2 + ci) * 9 + tap];
        }
        for (int i = tid; i < 792; i += 256) {
            int ci = i / 396, r = i - ci * 396;
            int row = r / 66, col = r - row * 66;
            int t_in = t0 + row - 1, f_in = f0 + col - 1;
            float v = 0.f;
            if (t_in >= 0 && t_in < Tt && f_in >= 0 && f_in < Ff)
                v = x1[((size_t)(b * 2 + ci) * Tt + t_in) * Ff + f_in];
            xs[ci][row][col] = v;
        }
        __syncthreads();

        float acc[2][16];
        #pragma unroll
        for (int q = 0; q < 2; q++)
            #pragma unroll
            for (int j = 0; j < 16; j++) acc[q][j] = 0.f;

        #pragma unroll
        for (int ci = 0; ci < 2; ci++) {
            float win[4][3];
            #pragma unroll
            for (int r = 0; r < 4; r++)
                #pragma unroll
                for (int c = 0; c < 3; c++)
                    win[r][c] = xs[ci][2 * tr + r][fl + c];
            #pragma unroll
            for (int dt = 0; dt < 3; dt++)
                #pragma unroll
                for (int kf = 0; kf < 3; kf++) {
                    float xv0 = win[dt][kf];
                    float xv1 = win[dt + 1][kf];
                    const float* wrow = wl + (ci * 9 + dt * 3 + kf) * 32 + h * 8;
                    float wv[16];
                    *(float4*)(wv)      = *(const float4*)(wrow);
                    *(float4*)(wv + 4)  = *(const float4*)(wrow + 4);
                    *(float4*)(wv + 8)  = *(const float4*)(wrow + 16);
                    *(float4*)(wv + 12) = *(const float4*)(wrow + 20);
                    #pragma unroll
                    for (int j = 0; j < 16; j++) {
                        acc[0][j] = fmaf(xv0, wv[j], acc[0][j]);
                        acc[1][j] = fmaf(xv1, wv[j], acc[1][j]);
                    }
                }
        }

        #pragma unroll
        for (int q = 0; q < 2; q++) {
            int t = t0 + 2 * tr + q;
            int fp = f0 + fl + 8;
            int sw = fp & 1;
            char* cell = bufA + ((size_t)(b * TROW + t + 8) * FROW + fp) * CELL;
            unsigned short hv[8];
            #pragma unroll
            for (int j = 0; j < 8; j++) {
                int ca = h * 8 + j, cg = 16 + h * 8 + j;
                float av = acc[q][j]     * bnsL[ca] + bnoL[ca];
                float gv = acc[q][8 + j] * bnsL[cg] + bnoL[cg];
                hv[j] = hbits(fast_tanh(av) * fast_sigmoid(gv));
            }
            uint4 P;
            P.x = (unsigned)hv[0] | ((unsigned)hv[1] << 16);
            P.y = (unsigned)hv[2] | ((unsigned)hv[3] << 16);
            P.z = (unsigned)hv[4] | ((unsigned)hv[5] << 16);
            P.w = (unsigned)hv[6] | ((unsigned)hv[7] << 16);
            *(uint4*)(cell + ((h ^ sw) * 16)) = P;
        }
    }
}

// ---------- convs 2-4: MFMA implicit GEMM, fp16 activations + fp16 hi/lo weights
// (2-pass, dual accumulators, combined at epilogue). r9 block structure:
// 4 outputs {t0,t0+d,t0+2d,t0+3d} x 128 f, 6 staged rows, 4 waves. ----------
template<int DIL, int WRITE_F32>
__global__ __launch_bounds__(256, 2)
void gate_mfma(const char* __restrict__ actIn, const char* __restrict__ wpre,
               const float* __restrict__ bpre, char* __restrict__ outBuf)
{
    __shared__ char actL[32768];   // stage uses 6*4608=27648; epilogue f32 needs 32768
    const int tg = blockIdx.x, fh = blockIdx.y, b = blockIdx.z;
    const int tid = threadIdx.x;            // 0..255
    const int w = tid >> 6, lane = tid & 63;
    const int n = lane & 15, q = lane >> 4;
    const int tsel = w >> 1, fsel = w & 1;
    constexpr int GPC = 128 / DIL;          // t-groups per residue class
    const int rcl = tg / GPC, m = tg - rcl * GPC;
    const int t0 = rcl + 4 * m * DIL;
    const int f0 = fh * 128;

    // A-fragments: plane0 = hi, plane1 = lo*2048 (fp16)
    half8 aH[5][2], aL[5][2];
    #pragma unroll
    for (int ks = 0; ks < 5; ks++)
        #pragma unroll
        for (int ct = 0; ct < 2; ct++) {
            int co = ct * 16 + n;
            int sub = q ^ (co & 3);
            aH[ks][ct] = *(const half8*)(wpre + (size_t)((0 * 5 + ks) * 32 + co) * 64 + sub * 16);
            aL[ks][ct] = *(const half8*)(wpre + (size_t)((5 + ks) * 32 + co) * 64 + sub * 16);
        }

    // stage 6 rows (144 cells x 32 B = 4608 B each = 288 16-B chunks)
    #pragma unroll
    for (int i = 0; i < 6; i++) {
        int tp = t0 + 8 + (i - 1) * DIL;
        const char* src = actIn + ((size_t)(b * TROW + tp) * FROW + f0) * CELL;
        char* dst = actL + i * WROWB;
        GLOAD_LDS(src + tid * 16, dst + tid * 16);
        if (tid < 64)   // chunks 224..287 (224-255 re-staged, benign)
            GLOAD_LDS(src + (224 + tid) * 16, dst + (224 + tid) * 16);
    }
    __syncthreads();

    const int fbl = fsel * 64;
    f32x4 accH[2][4][2] = {}, accL[2][4][2] = {};   // [tj][nt][ct]

    #pragma unroll
    for (int ks = 0; ks < 5; ks++) {
        const int tapA = 2 * ks;
        const int tapB = (2 * ks + 1 > 8) ? 8 : 2 * ks + 1;
        const int rowA = tapA / 3, dfA = (tapA % 3 - 1) * DIL;
        const int rowB = tapB / 3, dfB = (tapB % 3 - 1) * DIL;
        int tapSel = q >> 1;
        int rowt = tapSel ? rowB : rowA;
        int df  = tapSel ? dfB : dfA;
        int cih = q & 1;
        #pragma unroll
        for (int tj = 0; tj < 2; tj++) {
            const int jj = 2 * tsel + tj;
            const char* rbase = actL + (jj + rowt) * WROWB;
            #pragma unroll
            for (int nt = 0; nt < 4; nt++) {
                int fp = 8 + fbl + nt * 16 + n + df;
                const char* cell = rbase + fp * CELL;
                half8 bF = *(const half8*)(cell + ((cih ^ (fp & 1)) * 16));
                #pragma unroll
                for (int ct = 0; ct < 2; ct++) {
                    accH[tj][nt][ct] = mfma_f16(aH[ks][ct], bF, accH[tj][nt][ct]);
                    accL[tj][nt][ct] = mfma_f16(aL[ks][ct], bF, accL[tj][nt][ct]);
                }
            }
        }
    }

    float4 bA = *(const float4*)(bpre + q * 4);
    float4 bG = *(const float4*)(bpre + 16 + q * 4);
    const float CL = 4.8828125e-4f;   // 1/2048
    __syncthreads();   // done reading actL; reuse as epilogue buffer

    if (WRITE_F32) {
        float* Ef = (float*)actL;          // [jj(4)][c(16)][f_local(128)]
        #pragma unroll
        for (int tj = 0; tj < 2; tj++) {
            const int jj = 2 * tsel + tj;
            #pragma unroll
            for (int nt = 0; nt < 4; nt++) {
                float a0 = accH[tj][nt][0].x + CL * accL[tj][nt][0].x + bA.x;
                float a1 = accH[tj][nt][0].y + CL * accL[tj][nt][0].y + bA.y;
                float a2 = accH[tj][nt][0].z + CL * accL[tj][nt][0].z + bA.z;
                float a3 = accH[tj][nt][0].w + CL * accL[tj][nt][0].w + bA.w;
                float g0 = accH[tj][nt][1].x + CL * accL[tj][nt][1].x + bG.x;
                float g1 = accH[tj][nt][1].y + CL * accL[tj][nt][1].y + bG.y;
                float g2 = accH[tj][nt][1].z + CL * accL[tj][nt][1].z + bG.z;
                float g3 = accH[tj][nt][1].w + CL * accL[tj][nt][1].w + bG.w;
                float r[4];
                r[0] = fast_tanh(a0) * fast_sigmoid(g0);
                r[1] = fast_tanh(a1) * fast_sigmoid(g1);
                r[2] = fast_tanh(a2) * fast_sigmoid(g2);
                r[3] = fast_tanh(a3) * fast_sigmoid(g3);
                int fl = fbl + nt * 16 + n;
                #pragma unroll
                for (int j = 0; j < 4; j++)
                    Ef[(jj * 16 + q * 4 + j) * 128 + fl] = r[j];
            }
        }
        __syncthreads();
        float* gp = (float*)outBuf;
        #pragma unroll
        for (int k = 0; k < 8; k++) {
            int linear = k * 256 + tid;          // 2048 float4 chunks
            int jj2 = linear >> 9;
            int rem = linear & 511;
            int c = rem >> 5, fq = rem & 31;
            int tt = t0 + jj2 * DIL;
            *(float4*)(gp + (size_t)(b * 16 + c) * TF + tt * Ff + fh * 128 + fq * 4) =
                *(const float4*)(Ef + (jj2 * 16 + c) * 128 + fq * 4);
        }
    } else {
        char* Eo = actL;                   // [jj(4)][f_local(128)][32B]
        #pragma unroll
        for (int tj = 0; tj < 2; tj++) {
            const int jj = 2 * tsel + tj;
            #pragma unroll
            for (int nt = 0; nt < 4; nt++) {
                float a0 = accH[tj][nt][0].x + CL * accL[tj][nt][0].x + bA.x;
                float a1 = accH[tj][nt][0].y + CL * accL[tj][nt][0].y + bA.y;
                float a2 = accH[tj][nt][0].z + CL * accL[tj][nt][0].z + bA.z;
                float a3 = accH[tj][nt][0].w + CL * accL[tj][nt][0].w + bA.w;
                float g0 = accH[tj][nt][1].x + CL * accL[tj][nt][1].x + bG.x;
                float g1 = accH[tj][nt][1].y + CL * accL[tj][nt][1].y + bG.y;
                float g2 = accH[tj][nt][1].z + CL * accL[tj][nt][1].z + bG.z;
                float g3 = accH[tj][nt][1].w + CL * accL[tj][nt][1].w + bG.w;
                unsigned short hv[4];
                hv[0] = hbits(fast_tanh(a0) * fast_sigmoid(g0));
                hv[1] = hbits(fast_tanh(a1) * fast_sigmoid(g1));
                hv[2] = hbits(fast_tanh(a2) * fast_sigmoid(g2));
                hv[3] = hbits(fast_tanh(a3) * fast_sigmoid(g3));
                int fl = fbl + nt * 16 + n;
                int sw = (fh * 128 + fl + 8) & 1;
                uint2 pk;
                pk.x = (unsigned)hv[0] | ((unsigned)hv[1] << 16);
                pk.y = (unsigned)hv[2] | ((unsigned)hv[3] << 16);
                char* base = Eo + (jj * 128 + fl) * CELL;
                *(uint2*)(base + ((q >> 1) ^ sw) * 16 + (q & 1) * 8) = pk;
            }
        }
        __syncthreads();
        #pragma unroll
        for (int k = 0; k < 4; k++) {
            int linear = k * 256 + tid;          // 1024 x 16-B chunks, 256/t-row
            int jj2 = linear >> 8;
            int idx = linear & 255;
            int tt = t0 + jj2 * DIL;
            char* dstRow = outBuf + ((size_t)(b * TROW + tt + 8) * FROW + fh * 128 + 8) * CELL;
            *(uint4*)(dstRow + idx * 16) = *(const uint4*)(Eo + jj2 * 4096 + idx * 16);
        }
    }
}

// ---------- grouped GRU (H=2) + fused out_w partial dot ----------
// 3-buffer LDS-DMA pipeline, staged 2 chunks ahead, vmcnt(48) steady state.
// part layout: [b][g][fsl(4)][tpair(256)][lane(64)][2]
__global__ __launch_bounds__(64)
void gru_kernel(const float* __restrict__ xin, const float* __restrict__ wih,
                const float* __restrict__ whh, const float* __restrict__ bih,
                const float* __restrict__ bhh, const float* __restrict__ out_w,
                float* __restrict__ part)
{
    __shared__ float ldsF[3 * 4096];
    const int lane = threadIdx.x;
    const int fsl = blockIdx.x & 3;
    const int g = (blockIdx.x >> 2) & 7;
    const int b = blockIdx.x >> 5;

    const float L2E = 1.4426950408889634f;
    float2 WiX[3], WiY[3], WhX[3], WhY[3], Bi[3], Bh[3];
    #pragma unroll
    for (int p = 0; p < 3; p++) {
        WiX[p] = make_float2(wih[g * 12 + (2 * p) * 2 + 0] * L2E, wih[g * 12 + (2 * p + 1) * 2 + 0] * L2E);
        WiY[p] = make_float2(wih[g * 12 + (2 * p) * 2 + 1] * L2E, wih[g * 12 + (2 * p + 1) * 2 + 1] * L2E);
        WhX[p] = make_float2(whh[g * 12 + (2 * p) * 2 + 0] * L2E, whh[g * 12 + (2 * p + 1) * 2 + 0] * L2E);
        WhY[p] = make_float2(whh[g * 12 + (2 * p) * 2 + 1] * L2E, whh[g * 12 + (2 * p + 1) * 2 + 1] * L2E);
        Bi[p] = make_float2(bih[g * 6 + 2 * p] * L2E, bih[g * 6 + 2 * p + 1] * L2E);
        Bh[p] = make_float2(bhh[g * 6 + 2 * p] * L2E, bhh[g * 6 + 2 * p + 1] * L2E);
    }
    const float ow0 = out_w[2 * g], ow1 = out_w[2 * g + 1];

    const int sub = lane & 15, cch = (lane >> 4) & 1, tpr = lane >> 5;
    const float* gsrc = xin + ((size_t)(b * Cc + 2 * g + cch) * Tt + tpr) * Ff + fsl * 64 + sub * 4;

    float* poBase = part + ((size_t)((b * 8 + g) * 4 + fsl)) * 32768;

    #define STAGE(bsel, chunk)                                                \
    {                                                                         \
        char* ldst = (char*)(ldsF + (bsel) * 4096);                           \
        const float* gs = gsrc + (size_t)(chunk) * 32 * Ff;                   \
        _Pragma("unroll")                                                     \
        for (int j = 0; j < 16; j++)                                          \
            GLOAD_LDS(gs + 2 * j * Ff, ldst + j * 1024);                      \
    }

    float2 hP = make_float2(0.f, 0.f);
    STAGE(0, 0); STAGE(1, 1); STAGE(2, 2);

    for (int k = 0; k < 16; k++) {
        if (k) {
            int cs = k + 2; if (cs >= 16) cs -= 16;
            int bs = k + 2; bs -= (bs / 3) * 3;
            STAGE(bs, cs);
            __builtin_amdgcn_sched_barrier(0);
            __builtin_amdgcn_s_waitcnt(WAIT_VM48);
            __builtin_amdgcn_sched_barrier(0);
        } else {
            __builtin_amdgcn_sched_barrier(0);
            __builtin_amdgcn_s_waitcnt(WAIT_VM32);
            __builtin_amdgcn_sched_barrier(0);
        }
        int bc = k - (k / 3) * 3;
        const float* cbase = ldsF + bc * 4096;
        float2 outR[16];
        #pragma unroll
        for (int tt = 0; tt < 32; tt++) {
            const float* cell = cbase + (tt >> 1) * 256 + (tt & 1) * 128;
            float x0 = cell[lane];
            float x1 = cell[64 + lane];
            float2 giR = f2fma(WiY[0], x1, f2fma(WiX[0], x0, Bi[0]));
            float2 giZ = f2fma(WiY[1], x1, f2fma(WiX[1], x0, Bi[1]));
            float2 giN = f2fma(WiY[2], x1, f2fma(WiX[2], x0, Bi[2]));
            float2 ghR = f2fma(WhY[0], hP.y, f2fma(WhX[0], hP.x, Bh[0]));
            float2 ghZ = f2fma(WhY[1], hP.y, f2fma(WhX[1], hP.x, Bh[1]));
            float2 ghN = f2fma(WhY[2], hP.y, f2fma(WhX[2], hP.x, Bh[2]));
            float2 rP = sig2(make_float2(giR.x + ghR.x, giR.y + ghR.y));
            float2 zP = sig2(make_float2(giZ.x + ghZ.x, giZ.y + ghZ.y));
            float2 nP = tanh2(make_float2(fmaf(rP.x, ghN.x, giN.x), fmaf(rP.y, ghN.y, giN.y)));
            hP = make_float2(fmaf(zP.x, hP.x - nP.x, nP.x), fmaf(zP.y, hP.y - nP.y, nP.y));
            float o = fmaf(hP.x, ow0, hP.y * ow1);
            if (tt & 1) outR[tt >> 1].y = o; else outR[tt >> 1].x = o;
        }
        #pragma unroll
        for (int j = 0; j < 16; j++)
            *(float2*)(poBase + (k * 16 + j) * 128 + lane * 2) = outR[j];
    }
    #undef STAGE
}

// sum 8 group partials + out_b -> (B,1,T,F)
__global__ __launch_bounds__(256)
void out_kernel(const float* __restrict__ part, const float* __restrict__ out_b,
                float* __restrict__ out)
{
    int idx = blockIdx.x * 256 + threadIdx.x;    // 524288 total: [b][tpair][f]
    int f = idx & 255;
    int tp = (idx >> 8) & 255;
    int b = idx >> 16;
    int fsl = f >> 6, ln = f & 63;
    const float* base = part + ((size_t)(b * 8) * 4 + fsl) * 32768 + tp * 128 + ln * 2;
    float ob = out_b[0];
    float s0 = ob, s1 = ob;
    #pragma unroll
    for (int g = 0; g < 8; g++) {
        float2 v = *(const float2*)(base + (size_t)g * 131072);
        s0 += v.x; s1 += v.y;
    }
    float* op = out + ((size_t)b * Tt + 2 * tp) * Ff + f;
    op[0] = s0;
    op[Ff] = s1;
}

extern "C" void kernel_launch(void* const* d_in, const int* in_sizes, int n_in,
                              void* d_out, int out_size, void* d_ws, size_t ws_size,
                              hipStream_t stream) {
    char* bufA = (char*)d_ws;                         // 36.8 MB fp16-cell buf (conv1/conv3 out; later gru part)
    char* bufB = bufA + BUFBYTES;                     // 36.8 MB fp16-cell buf (conv2 out)
    float* gruF = (float*)(bufB + BUFBYTES);          // 67.1 MB fp32 conv4 out
    char* wpre = (char*)gruF + (size_t)Bb * Cc * TF * 4;
    float* bpre = (float*)(wpre + 3 * 20480);

    setup_all<<<787 + 4096, 256, 0, stream>>>(
        (const float*)d_in[0],
        (const float*)d_in[1],  (const float*)d_in[2],  (const float*)d_in[3],
        (const float*)d_in[4],  (const float*)d_in[5],  (const float*)d_in[6],
        (const float*)d_in[7],  (const float*)d_in[8],  (const float*)d_in[9],
        (const float*)d_in[10], (const float*)d_in[11], (const float*)d_in[12],
        (const float*)d_in[13], (const float*)d_in[14], (const float*)d_in[15],
        (const float*)d_in[16], (const float*)d_in[17], (const float*)d_in[18],
        (const float*)d_in[19], (const float*)d_in[20], (const float*)d_in[21],
        (const float*)d_in[22], (const float*)d_in[23], (const float*)d_in[24],
        bufA, bufB, wpre, bpre);

    dim3 grid(128, 2, Bb), blk(256);
    gate_mfma<2, 0><<<grid, blk, 0, stream>>>(bufA, wpre,         bpre,      bufB);
    gate_mfma<4, 0><<<grid, blk, 0, stream>>>(bufB, wpre + 20480, bpre + 32, bufA);
    gate_mfma<8, 1><<<grid, blk, 0, stream>>>(bufA, wpre + 40960, bpre + 64, (char*)gruF);

    // GRU reads fp32 gruF, writes partials into bufA (conv stages done with it)
    gru_kernel<<<Bb * 8 * 4, 64, 0, stream>>>(
        gruF, (const float*)d_in[25], (const float*)d_in[26], (const float*)d_in[27],
        (const float*)d_in[28], (const float*)d_in[29], (float*)bufA);

    out_kernel<<<2048, 256, 0, stream>>>(
        (const float*)bufA, (const float*)d_in[30], (float*)d_out);
}

// Round 14
// 273.555 us; speedup vs baseline: 1.3905x; 1.1074x over previous
//
#include <hip/hip_runtime.h>

#define Bb 8
#define Tt 512
#define Ff 256
#define Cc 16
#define TF (Tt*Ff)
#define TROW 528
#define FROW 272
#define CELL 32
#define WROWB (144*CELL)                           // 4608 B per staged window row
#define BUFBYTES ((size_t)Bb*TROW*FROW*CELL)       // 36,765,696

typedef _Float16 half8 __attribute__((ext_vector_type(8)));
typedef __attribute__((ext_vector_type(4))) float f32x4;

typedef const __attribute__((address_space(1))) void* gas1_t;
typedef __attribute__((address_space(3))) void* las3_t;
#define GLOAD_LDS(g, l) __builtin_amdgcn_global_load_lds((gas1_t)(const void*)(g), (las3_t)(void*)(l), 16, 0, 0)

// s_waitcnt imm: vmcnt[3:0]+[15:14], expcnt[6:4]=7, lgkmcnt[11:8]=15 (no wait)
#define WAIT_VM8  0x0F78
#define WAIT_VM24 0x4F78
#define WAIT_VM40 0x8F78

__device__ __forceinline__ float fexp2(float x) { return __builtin_amdgcn_exp2f(x); }

__device__ __forceinline__ float fast_sigmoid(float x) {
    return __builtin_amdgcn_rcpf(1.0f + fexp2(-1.4426950408889634f * x));
}
__device__ __forceinline__ float fast_tanh(float x) {
    return 1.0f - 2.0f * __builtin_amdgcn_rcpf(fexp2(2.8853900817779268f * x) + 1.0f);
}

__device__ __forceinline__ unsigned short hbits(float x) {
    _Float16 h = (_Float16)x;
    return __builtin_bit_cast(unsigned short, h);
}
__device__ __forceinline__ float h2f(unsigned short u) {
    return (float)__builtin_bit_cast(_Float16, u);
}
__device__ __forceinline__ f32x4 mfma_f16(half8 a, half8 b, f32x4 c) {
    return __builtin_amdgcn_mfma_f32_16x16x32_f16(a, b, c, 0, 0, 0);
}
// VALU-rate swap of lanes l and l^8 within each row of 16 (DPP row_ror:8)
__device__ __forceinline__ float dpp_swap8(float x) {
    int xi = __builtin_bit_cast(int, x);
    int r = __builtin_amdgcn_mov_dpp(xi, 0x128, 0xf, 0xf, true);
    return __builtin_bit_cast(float, r);
}

// ---------- merged setup: blocks 0-2 = BN-fold + fp16 hi/lo weight planes;
// blocks 3..786 = zero halo pads; blocks 787.. = gate1 conv ----------
__global__ __launch_bounds__(256)
void setup_all(const float* __restrict__ x1, const float* __restrict__ w1, const float* __restrict__ b1,
               const float* __restrict__ gm1, const float* __restrict__ bt1,
               const float* __restrict__ mn1, const float* __restrict__ vr1,
               const float* __restrict__ w2, const float* __restrict__ b2, const float* __restrict__ gm2,
               const float* __restrict__ bt2, const float* __restrict__ mn2, const float* __restrict__ vr2,
               const float* __restrict__ w3, const float* __restrict__ b3, const float* __restrict__ gm3,
               const float* __restrict__ bt3, const float* __restrict__ mn3, const float* __restrict__ vr3,
               const float* __restrict__ w4, const float* __restrict__ b4, const float* __restrict__ gm4,
               const float* __restrict__ bt4, const float* __restrict__ mn4, const float* __restrict__ vr4,
               char* __restrict__ bufA, char* __restrict__ bufB,
               char* __restrict__ wpreAll, float* __restrict__ bpreAll)
{
    const int blk = blockIdx.x;
    const int tid = threadIdx.x;
    if (blk < 3) {
        const float *w, *bias, *gamma, *beta, *mean, *var;
        if (blk == 0)      { w = w2; bias = b2; gamma = gm2; beta = bt2; mean = mn2; var = vr2; }
        else if (blk == 1) { w = w3; bias = b3; gamma = gm3; beta = bt3; mean = mn3; var = vr3; }
        else               { w = w4; bias = b4; gamma = gm4; beta = bt4; mean = mn4; var = vr4; }
        char* wpre = wpreAll + blk * 20480;
        float* bpre = bpreAll + blk * 32;
        if (tid < 32) {
            float s = gamma[tid] * rsqrtf(var[tid] + 1e-5f);
            bpre[tid] = (bias[tid] - mean[tid]) * s + beta[tid];
        }
        for (int i = tid; i < 4608; i += 256) {
            int co = i / 144, r = i - co * 144;
            int ci = r / 9, tap = r - ci * 9;
            float s = gamma[co] * rsqrtf(var[co] + 1e-5f);
            float wv = w[(co * 16 + ci) * 9 + tap] * s;
            unsigned short hi = hbits(wv);
            unsigned short lo = hbits((wv - h2f(hi)) * 2048.0f);
            int ks = tap >> 1, tp = tap & 1;
            int kl = tp * 16 + ci;
            int qq = kl >> 3, jj = kl & 7;
            int sub = qq ^ (co & 3);
            *(unsigned short*)(wpre + ((0 * 5 + ks) * 32 + co) * 64 + sub * 16 + jj * 2) = hi;
            *(unsigned short*)(wpre + ((1 * 5 + ks) * 32 + co) * 64 + sub * 16 + jj * 2) = lo;
        }
        for (int i = tid; i < 1024; i += 256) {
            int p = i >> 9, rem = i & 511;
            int co = rem >> 4, kl = 16 + (rem & 15);
            int qq = kl >> 3, jj = kl & 7;
            int sub = qq ^ (co & 3);
            *(unsigned short*)(wpre + ((p * 5 + 4) * 32 + co) * 64 + sub * 16 + jj * 2) = 0;
        }
    } else if (blk < 787) {
        int idx = (blk - 3) * 256 + tid;      // 200704 halo cells total
        int which = idx >= 100352;
        int r0 = which ? idx - 100352 : idx;
        int b = r0 / 12544, c = r0 - b * 12544;
        int tp, fp;
        if (c < 4352) { int row = c / 272; fp = c - row * 272; tp = row < 8 ? row : 512 + row; }
        else { int c2 = c - 4352; tp = 8 + (c2 >> 4); int fi = c2 & 15; fp = fi < 8 ? fi : 256 + fi; }
        char* base = (which ? bufB : bufA) + ((size_t)(b * TROW + tp) * FROW + fp) * CELL;
        float4 z = make_float4(0.f, 0.f, 0.f, 0.f);
        float4* p = (float4*)base;
        p[0] = z; p[1] = z;
    } else {
        // ---- gate1 conv (CIN=2, dil=1), tiled, fp16 cell output ----
        __shared__ float xs[2][6][66];
        __shared__ float wl[18 * 32];
        __shared__ float bnsL[32], bnoL[32];
        int bb = blk - 787;                   // 4096 blocks: [b(8)][ty(128)][fx(4)]
        int fx = bb & 3;
        int ty = (bb >> 2) & 127;
        int b  = bb >> 9;
        const int f0 = fx * 64;
        const int t0 = ty * 4;
        const int fl = tid & 63;
        const int tr = (tid >> 6) & 1;
        const int h  = tid >> 7;

        if (tid < 32) {
            float s = gm1[tid] * rsqrtf(vr1[tid] + 1e-5f);
            bnsL[tid] = s;
            bnoL[tid] = (b1[tid] - mn1[tid]) * s + bt1[tid];
        }
        for (int i = tid; i < 576; i += 256) {
            int co = i & 31, rest = i >> 5;
            int ci = rest / 9, tap = rest - ci * 9;
            wl[rest * 32 + co] = w1[(co * 2 + ci) * 9 + tap];
        }
        for (int i = tid; i < 792; i += 256) {
            int ci = i / 396, r = i - ci * 396;
            int row = r / 66, col = r - row * 66;
            int t_in = t0 + row - 1, f_in = f0 + col - 1;
            float v = 0.f;
            if (t_in >= 0 && t_in < Tt && f_in >= 0 && f_in < Ff)
                v = x1[((size_t)(b * 2 + ci) * Tt + t_in) * Ff + f_in];
            xs[ci][row][col] = v;
        }
        __syncthreads();

        float acc[2][16];
        #pragma unroll
        for (int q = 0; q < 2; q++)
            #pragma unroll
            for (int j = 0; j < 16; j++) acc[q][j] = 0.f;

        #pragma unroll
        for (int ci = 0; ci < 2; ci++) {
            float win[4][3];
            #pragma unroll
            for (int r = 0; r < 4; r++)
                #pragma unroll
                for (int c = 0; c < 3; c++)
                    win[r][c] = xs[ci][2 * tr + r][fl + c];
            #pragma unroll
            for (int dt = 0; dt < 3; dt++)
                #pragma unroll
                for (int kf = 0; kf < 3; kf++) {
                    float xv0 = win[dt][kf];
                    float xv1 = win[dt + 1][kf];
                    const float* wrow = wl + (ci * 9 + dt * 3 + kf) * 32 + h * 8;
                    float wv[16];
                    *(float4*)(wv)      = *(const float4*)(wrow);
                    *(float4*)(wv + 4)  = *(const float4*)(wrow + 4);
                    *(float4*)(wv + 8)  = *(const float4*)(wrow + 16);
                    *(float4*)(wv + 12) = *(const float4*)(wrow + 20);
                    #pragma unroll
                    for (int j = 0; j < 16; j++) {
                        acc[0][j] = fmaf(xv0, wv[j], acc[0][j]);
                        acc[1][j] = fmaf(xv1, wv[j], acc[1][j]);
                    }
                }
        }

        #pragma unroll
        for (int q = 0; q < 2; q++) {
            int t = t0 + 2 * tr + q;
            int fp = f0 + fl + 8;
            int sw = fp & 1;
            char* cell = bufA + ((size_t)(b * TROW + t + 8) * FROW + fp) * CELL;
            unsigned short hv[8];
            #pragma unroll
            for (int j = 0; j < 8; j++) {
                int ca = h * 8 + j, cg = 16 + h * 8 + j;
                float av = acc[q][j]     * bnsL[ca] + bnoL[ca];
                float gv = acc[q][8 + j] * bnsL[cg] + bnoL[cg];
                hv[j] = hbits(fast_tanh(av) * fast_sigmoid(gv));
            }
            uint4 P;
            P.x = (unsigned)hv[0] | ((unsigned)hv[1] << 16);
            P.y = (unsigned)hv[2] | ((unsigned)hv[3] << 16);
            P.z = (unsigned)hv[4] | ((unsigned)hv[5] << 16);
            P.w = (unsigned)hv[6] | ((unsigned)hv[7] << 16);
            *(uint4*)(cell + ((h ^ sw) * 16)) = P;
        }
    }
}

// ---------- convs 2-4: MFMA implicit GEMM, fp16 activations + fp16 hi/lo weights
// (2-pass, dual accumulators). 4 outputs {t0..t0+3d} x 128 f, 6 staged rows. ----
template<int DIL, int WRITE_F32>
__global__ __launch_bounds__(256, 2)
void gate_mfma(const char* __restrict__ actIn, const char* __restrict__ wpre,
               const float* __restrict__ bpre, char* __restrict__ outBuf)
{
    __shared__ char actL[32768];
    const int tg = blockIdx.x, fh = blockIdx.y, b = blockIdx.z;
    const int tid = threadIdx.x;
    const int w = tid >> 6, lane = tid & 63;
    const int n = lane & 15, q = lane >> 4;
    const int tsel = w >> 1, fsel = w & 1;
    constexpr int GPC = 128 / DIL;
    const int rcl = tg / GPC, m = tg - rcl * GPC;
    const int t0 = rcl + 4 * m * DIL;
    const int f0 = fh * 128;

    half8 aH[5][2], aL[5][2];
    #pragma unroll
    for (int ks = 0; ks < 5; ks++)
        #pragma unroll
        for (int ct = 0; ct < 2; ct++) {
            int co = ct * 16 + n;
            int sub = q ^ (co & 3);
            aH[ks][ct] = *(const half8*)(wpre + (size_t)((0 * 5 + ks) * 32 + co) * 64 + sub * 16);
            aL[ks][ct] = *(const half8*)(wpre + (size_t)((5 + ks) * 32 + co) * 64 + sub * 16);
        }

    #pragma unroll
    for (int i = 0; i < 6; i++) {
        int tp = t0 + 8 + (i - 1) * DIL;
        const char* src = actIn + ((size_t)(b * TROW + tp) * FROW + f0) * CELL;
        char* dst = actL + i * WROWB;
        GLOAD_LDS(src + tid * 16, dst + tid * 16);
        if (tid < 64)
            GLOAD_LDS(src + (224 + tid) * 16, dst + (224 + tid) * 16);
    }
    __syncthreads();

    const int fbl = fsel * 64;
    f32x4 accH[2][4][2] = {}, accL[2][4][2] = {};

    #pragma unroll
    for (int ks = 0; ks < 5; ks++) {
        const int tapA = 2 * ks;
        const int tapB = (2 * ks + 1 > 8) ? 8 : 2 * ks + 1;
        const int rowA = tapA / 3, dfA = (tapA % 3 - 1) * DIL;
        const int rowB = tapB / 3, dfB = (tapB % 3 - 1) * DIL;
        int tapSel = q >> 1;
        int rowt = tapSel ? rowB : rowA;
        int df  = tapSel ? dfB : dfA;
        int cih = q & 1;
        #pragma unroll
        for (int tj = 0; tj < 2; tj++) {
            const int jj = 2 * tsel + tj;
            const char* rbase = actL + (jj + rowt) * WROWB;
            #pragma unroll
            for (int nt = 0; nt < 4; nt++) {
                int fp = 8 + fbl + nt * 16 + n + df;
                const char* cell = rbase + fp * CELL;
                half8 bF = *(const half8*)(cell + ((cih ^ (fp & 1)) * 16));
                #pragma unroll
                for (int ct = 0; ct < 2; ct++) {
                    accH[tj][nt][ct] = mfma_f16(aH[ks][ct], bF, accH[tj][nt][ct]);
                    accL[tj][nt][ct] = mfma_f16(aL[ks][ct], bF, accL[tj][nt][ct]);
                }
            }
        }
    }

    float4 bA = *(const float4*)(bpre + q * 4);
    float4 bG = *(const float4*)(bpre + 16 + q * 4);
    const float CL = 4.8828125e-4f;   // 1/2048
    __syncthreads();

    if (WRITE_F32) {
        float* Ef = (float*)actL;
        #pragma unroll
        for (int tj = 0; tj < 2; tj++) {
            const int jj = 2 * tsel + tj;
            #pragma unroll
            for (int nt = 0; nt < 4; nt++) {
                float a0 = accH[tj][nt][0].x + CL * accL[tj][nt][0].x + bA.x;
                float a1 = accH[tj][nt][0].y + CL * accL[tj][nt][0].y + bA.y;
                float a2 = accH[tj][nt][0].z + CL * accL[tj][nt][0].z + bA.z;
                float a3 = accH[tj][nt][0].w + CL * accL[tj][nt][0].w + bA.w;
                float g0 = accH[tj][nt][1].x + CL * accL[tj][nt][1].x + bG.x;
                float g1 = accH[tj][nt][1].y + CL * accL[tj][nt][1].y + bG.y;
                float g2 = accH[tj][nt][1].z + CL * accL[tj][nt][1].z + bG.z;
                float g3 = accH[tj][nt][1].w + CL * accL[tj][nt][1].w + bG.w;
                float r[4];
                r[0] = fast_tanh(a0) * fast_sigmoid(g0);
                r[1] = fast_tanh(a1) * fast_sigmoid(g1);
                r[2] = fast_tanh(a2) * fast_sigmoid(g2);
                r[3] = fast_tanh(a3) * fast_sigmoid(g3);
                int fl = fbl + nt * 16 + n;
                #pragma unroll
                for (int j = 0; j < 4; j++)
                    Ef[(jj * 16 + q * 4 + j) * 128 + fl] = r[j];
            }
        }
        __syncthreads();
        float* gp = (float*)outBuf;
        #pragma unroll
        for (int k = 0; k < 8; k++) {
            int linear = k * 256 + tid;
            int jj2 = linear >> 9;
            int rem = linear & 511;
            int c = rem >> 5, fq = rem & 31;
            int tt = t0 + jj2 * DIL;
            *(float4*)(gp + (size_t)(b * 16 + c) * TF + tt * Ff + fh * 128 + fq * 4) =
                *(const float4*)(Ef + (jj2 * 16 + c) * 128 + fq * 4);
        }
    } else {
        char* Eo = actL;
        #pragma unroll
        for (int tj = 0; tj < 2; tj++) {
            const int jj = 2 * tsel + tj;
            #pragma unroll
            for (int nt = 0; nt < 4; nt++) {
                float a0 = accH[tj][nt][0].x + CL * accL[tj][nt][0].x + bA.x;
                float a1 = accH[tj][nt][0].y + CL * accL[tj][nt][0].y + bA.y;
                float a2 = accH[tj][nt][0].z + CL * accL[tj][nt][0].z + bA.z;
                float a3 = accH[tj][nt][0].w + CL * accL[tj][nt][0].w + bA.w;
                float g0 = accH[tj][nt][1].x + CL * accL[tj][nt][1].x + bG.x;
                float g1 = accH[tj][nt][1].y + CL * accL[tj][nt][1].y + bG.y;
                float g2 = accH[tj][nt][1].z + CL * accL[tj][nt][1].z + bG.z;
                float g3 = accH[tj][nt][1].w + CL * accL[tj][nt][1].w + bG.w;
                unsigned short hv[4];
                hv[0] = hbits(fast_tanh(a0) * fast_sigmoid(g0));
                hv[1] = hbits(fast_tanh(a1) * fast_sigmoid(g1));
                hv[2] = hbits(fast_tanh(a2) * fast_sigmoid(g2));
                hv[3] = hbits(fast_tanh(a3) * fast_sigmoid(g3));
                int fl = fbl + nt * 16 + n;
                int sw = (fh * 128 + fl + 8) & 1;
                uint2 pk;
                pk.x = (unsigned)hv[0] | ((unsigned)hv[1] << 16);
                pk.y = (unsigned)hv[2] | ((unsigned)hv[3] << 16);
                char* base = Eo + (jj * 128 + fl) * CELL;
                *(uint2*)(base + ((q >> 1) ^ sw) * 16 + (q & 1) * 8) = pk;
            }
        }
        __syncthreads();
        #pragma unroll
        for (int k = 0; k < 4; k++) {
            int linear = k * 256 + tid;
            int jj2 = linear >> 8;
            int idx = linear & 255;
            int tt = t0 + jj2 * DIL;
            char* dstRow = outBuf + ((size_t)(b * TROW + tt + 8) * FROW + fh * 128 + 8) * CELL;
            *(uint4*)(dstRow + idx * 16) = *(const uint4*)(Eo + jj2 * 4096 + idx * 16);
        }
    }
}

// ---------- grouped GRU: unit-split across lane pairs (DPP row_ror:8) ----------
// Wave = 32 sequences x 2 unit-lanes. 2 waves/block -> 512 waves = 2 waves/CU.
// 3-buffer wave-private LDS pipeline (8 KB chunks of 32 steps), in-order vmcnt.
// part layout: [b][g][fblk(8)][tpair(256)][u(2)][f32(32)][2]
__global__ __launch_bounds__(128)
void gru_kernel(const float* __restrict__ xin, const float* __restrict__ wih,
                const float* __restrict__ whh, const float* __restrict__ bih,
                const float* __restrict__ bhh, const float* __restrict__ out_w,
                float* __restrict__ part)
{
    __shared__ float ldsF[2][3 * 2048];   // per-wave 3 x 8 KB
    const int tid = threadIdx.x;
    const int wv = tid >> 6, lane = tid & 63;
    const int b = blockIdx.x >> 5;
    const int g = (blockIdx.x >> 2) & 7;
    const int fblk = (blockIdx.x & 3) * 2 + wv;
    const int f0 = fblk * 32;

    const int row = lane >> 4;
    const int u = (lane >> 3) & 1;
    const int fi = (lane & 7) | (row << 3);     // 0..31

    const float L2E = 1.4426950408889634f;
    // per-lane gate weights for unit u (gates p: 0=r,1=z,2=n); wih row = p*2+u
    float Wi0[3], Wi1[3], Whs[3], Who[3], Bi[3], Bh[3];
    #pragma unroll
    for (int p = 0; p < 3; p++) {
        int rw = p * 2 + u;
        Wi0[p] = wih[g * 12 + rw * 2 + 0] * L2E;
        Wi1[p] = wih[g * 12 + rw * 2 + 1] * L2E;
        Whs[p] = whh[g * 12 + rw * 2 + u] * L2E;
        Who[p] = whh[g * 12 + rw * 2 + (1 - u)] * L2E;
        Bi[p]  = bih[g * 6 + rw] * L2E;
        Bh[p]  = bhh[g * 6 + rw] * L2E;
    }
    const float ow = out_w[2 * g + u];

    // staging map: s = lane&7 (16B f-subchunk), p2 = lane>>3: c = p2&1, tr = p2>>1
    const int s = lane & 7, cch = (lane >> 3) & 1, trr = lane >> 4;
    const float* gsrc = xin + ((size_t)(b * Cc + 2 * g + cch) * Tt + trr) * Ff + f0 + s * 4;
    float* ldsW = ldsF[wv];

    float* poW = part + ((((size_t)(b * 8 + g) * 8 + fblk) * 256) * 128) + u * 64 + fi * 2;

    #define STAGE(bsel, chunk)                                                 \
    {                                                                          \
        char* ldst = (char*)(ldsW + (bsel) * 2048) + lane * 16;                \
        const float* gs = gsrc + (size_t)(chunk) * 32 * Ff;                    \
        _Pragma("unroll")                                                      \
        for (int i = 0; i < 8; i++)                                            \
            GLOAD_LDS(gs + i * 4 * Ff, ldst + i * 1024);                       \
    }

    float h = 0.f;
    STAGE(0, 0); STAGE(1, 1);

    for (int k = 0; k < 16; k++) {
        __builtin_amdgcn_sched_barrier(0);
        if (k == 0)      __builtin_amdgcn_s_waitcnt(WAIT_VM8);
        else if (k == 1) __builtin_amdgcn_s_waitcnt(WAIT_VM24);
        else             __builtin_amdgcn_s_waitcnt(WAIT_VM40);
        __builtin_amdgcn_sched_barrier(0);
        int bc = k - (k / 3) * 3;                 // k%3
        const float* cbase = ldsW + bc * 2048;
        float2 outR[16];
        #pragma unroll
        for (int tt = 0; tt < 32; tt++) {
            const float* cell = cbase + (tt >> 2) * 256 + (tt & 3) * 64;
            float x0 = cell[fi];
            float x1 = cell[32 + fi];
            float ho = dpp_swap8(h);
            float gir = fmaf(Wi1[0], x1, fmaf(Wi0[0], x0, Bi[0]));
            float giz = fmaf(Wi1[1], x1, fmaf(Wi0[1], x0, Bi[1]));
            float gin = fmaf(Wi1[2], x1, fmaf(Wi0[2], x0, Bi[2]));
            float ghr = fmaf(Who[0], ho, fmaf(Whs[0], h, Bh[0]));
            float ghz = fmaf(Who[1], ho, fmaf(Whs[1], h, Bh[1]));
            float ghn = fmaf(Who[2], ho, fmaf(Whs[2], h, Bh[2]));
            float r = __builtin_amdgcn_rcpf(1.f + fexp2(-(gir + ghr)));
            float z = __builtin_amdgcn_rcpf(1.f + fexp2(-(giz + ghz)));
            float an = fmaf(r, ghn, gin);
            float nv = fmaf(-2.f, __builtin_amdgcn_rcpf(fexp2(an + an) + 1.f), 1.f);
            h = fmaf(z, h - nv, nv);
            float o = h * ow;
            if (tt & 1) outR[tt >> 1].y = o; else outR[tt >> 1].x = o;
        }
        int cs = k + 2; cs &= 15;                 // re-stage 0/1 at tail (harmless)
        int bs = k + 2; bs -= (bs / 3) * 3;
        STAGE(bs, cs);
        #pragma unroll
        for (int j = 0; j < 16; j++)
            *(float2*)(poW + (k * 16 + j) * 128) = outR[j];
    }
    #undef STAGE
}

// sum 16 (g,u) partials + out_b -> (B,1,T,F)
__global__ __launch_bounds__(256)
void out_kernel(const float* __restrict__ part, const float* __restrict__ out_b,
                float* __restrict__ out)
{
    int idx = blockIdx.x * 256 + threadIdx.x;    // 524288 total: [b][tpair][f]
    int f = idx & 255;
    int tp = (idx >> 8) & 255;
    int b = idx >> 16;
    int fsl = f >> 5, fi = f & 31;
    const float* base = part + (size_t)b * 2097152 + (size_t)fsl * 32768 + tp * 128 + fi * 2;
    float ob = out_b[0];
    float s0 = ob, s1 = ob;
    #pragma unroll
    for (int g = 0; g < 8; g++)
        #pragma unroll
        for (int u = 0; u < 2; u++) {
            float2 v = *(const float2*)(base + (size_t)g * 262144 + u * 64);
            s0 += v.x; s1 += v.y;
        }
    float* op = out + ((size_t)b * Tt + 2 * tp) * Ff + f;
    op[0] = s0;
    op[Ff] = s1;
}

extern "C" void kernel_launch(void* const* d_in, const int* in_sizes, int n_in,
                              void* d_out, int out_size, void* d_ws, size_t ws_size,
                              hipStream_t stream) {
    char* bufA = (char*)d_ws;                         // 36.8 MB fp16-cell buf
    char* bufB = bufA + BUFBYTES;                     // 36.8 MB fp16-cell buf
    float* gruF = (float*)(bufB + BUFBYTES);          // 67.1 MB fp32 conv4 out
    char* wpre = (char*)gruF + (size_t)Bb * Cc * TF * 4;
    float* bpre = (float*)(wpre + 3 * 20480);
    float* partF = (float*)bufA;                      // 67.1 MB part spans bufA+bufB

    setup_all<<<787 + 4096, 256, 0, stream>>>(
        (const float*)d_in[0],
        (const float*)d_in[1],  (const float*)d_in[2],  (const float*)d_in[3],
        (const float*)d_in[4],  (const float*)d_in[5],  (const float*)d_in[6],
        (const float*)d_in[7],  (const float*)d_in[8],  (const float*)d_in[9],
        (const float*)d_in[10], (const float*)d_in[11], (const float*)d_in[12],
        (const float*)d_in[13], (const float*)d_in[14], (const float*)d_in[15],
        (const float*)d_in[16], (const float*)d_in[17], (const float*)d_in[18],
        (const float*)d_in[19], (const float*)d_in[20], (const float*)d_in[21],
        (const float*)d_in[22], (const float*)d_in[23], (const float*)d_in[24],
        bufA, bufB, wpre, bpre);

    dim3 grid(128, 2, Bb), blk(256);
    gate_mfma<2, 0><<<grid, blk, 0, stream>>>(bufA, wpre,         bpre,      bufB);
    gate_mfma<4, 0><<<grid, blk, 0, stream>>>(bufB, wpre + 20480, bpre + 32, bufA);
    gate_mfma<8, 1><<<grid, blk, 0, stream>>>(bufA, wpre + 40960, bpre + 64, (char*)gruF);

    gru_kernel<<<256, 128, 0, stream>>>(
        gruF, (const float*)d_in[25], (const float*)d_in[26], (const float*)d_in[27],
        (const float*)d_in[28], (const float*)d_in[29], partF);

    out_kernel<<<2048, 256, 0, stream>>>(
        partF, (const float*)d_in[30], (float*)d_out);
}